// Round 2
// baseline (86.085 us; speedup 1.0000x reference)
//
#include <hip/hip_runtime.h>

// ViT block with "quantum" VQC layers on MI355X — float32 I/O.
//
// VQC closed form: the 8-qubit circuit (RX data layer + RX weight layer +
// CNOT ring) reduces exactly to prefix products of cos(x_i + W_i):
//   z_0 = prod_{i=1..7} cos(th_i),  z_k = prod_{i=0..k} cos(th_i)  (k>=1)
// (product state -> CNOT ring is a basis permutation -> bit k becomes parity
// of bits 0..k; expectations of parities of independent bits factorize).
//
// R4 structure: grid = B*4 blocks (256 total, one per CU). Each block owns
// 64 query tokens; 1024 threads = 128 (token,head) pairs x 8 key-splits of
// 32 keys each (R3 was 512 thr x 4 splits: main loop was the critical path
// at only 2 waves/SIMD; this halves the serial loop and doubles TLP).
// Scores are bounded (|q.k|*0.5 <= 2) so plain exp-sum is exact-safe and
// split partials combine by addition in LDS. Softmax uses exp2 via
// __builtin_amdgcn_exp2f (v_exp_f32) with log2(e) folded into qh
// (base-invariant). Split-reduce is parallelized across 128 threads into Cs
// before the 64-thread MLP tail; tail weight loads are chunked 8-at-a-time
// to keep VGPR <= 128 (needed for 16 waves/CU).

#define SEQ 256
#define EMB 8
#define QG  64    // query tokens per block
#define NSPLIT 8  // key splits (32 keys each)

static __device__ __forceinline__ void load8f(const float* __restrict__ p, float v[8]) {
    float4 a = *reinterpret_cast<const float4*>(p);
    float4 b = *reinterpret_cast<const float4*>(p + 4);
    v[0] = a.x; v[1] = a.y; v[2] = a.z; v[3] = a.w;
    v[4] = b.x; v[5] = b.y; v[6] = b.z; v[7] = b.w;
}

static __device__ __forceinline__ void store8f(float* __restrict__ p, const float v[8]) {
    *reinterpret_cast<float4*>(p)     = make_float4(v[0], v[1], v[2], v[3]);
    *reinterpret_cast<float4*>(p + 4) = make_float4(v[4], v[5], v[6], v[7]);
}

// Closed-form 8-qubit VQC (see header comment).
static __device__ __forceinline__ void vqc8(const float in[8], const float W[8], float z[8]) {
    float c[8];
#pragma unroll
    for (int i = 0; i < 8; ++i) c[i] = __cosf(in[i] + W[i]);
    float t = c[1];
#pragma unroll
    for (int i = 2; i < 8; ++i) t *= c[i];
    z[0] = t;
    float acc = c[0];
#pragma unroll
    for (int i = 1; i < 8; ++i) { acc *= c[i]; z[i] = acc; }
}

static __device__ __forceinline__ void ln8(const float r[8], const float g[8], const float be[8], float o[8]) {
    float m = 0.f;
#pragma unroll
    for (int i = 0; i < 8; ++i) m += r[i];
    m *= 0.125f;
    float var = 0.f;
#pragma unroll
    for (int i = 0; i < 8; ++i) { float d = r[i] - m; var += d * d; }
    var *= 0.125f;
    float inv = rsqrtf(var + 1e-5f);
#pragma unroll
    for (int i = 0; i < 8; ++i) o[i] = (r[i] - m) * inv * g[i] + be[i];
}

__global__ __launch_bounds__(1024) void vitq_kernel(
    const float* __restrict__ x,
    const float* __restrict__ Wq, const float* __restrict__ Wk,
    const float* __restrict__ Wv, const float* __restrict__ Wc,
    const float* __restrict__ Wf,
    const float* __restrict__ w1, const float* __restrict__ b1,
    const float* __restrict__ w2, const float* __restrict__ b2,
    const float* __restrict__ g1, const float* __restrict__ be1,
    const float* __restrict__ g2, const float* __restrict__ be2,
    float* __restrict__ out)
{
    __shared__ float Ks[SEQ][EMB];                 // 8 KB
    __shared__ float Vs[SEQ][EMB];                 // 8 KB
    __shared__ float P[NSPLIT][2 * QG][5];         // 20 KB partials (stride 5 -> 2-way = free)
    __shared__ float Cs[QG][EMB];                  // 2 KB context rows

    const int bi  = blockIdx.x;
    const int b   = bi >> 2;          // batch
    const int g   = bi & 3;           // query group (64 tokens)
    const int tid = threadIdx.x;
    const int p   = tid & 127;        // (token,head) pair
    const int j   = tid >> 7;         // key split 0..7   (wave-uniform)
    const int sl  = p & 63;           // local token
    const int h   = p >> 6;           // head             (wave-uniform)
    const int s   = g * QG + sl;      // global token in batch

    const float* xb = x + ((size_t)b * SEQ) * EMB;

    // ---- Q for my (token,head) ----
    float xq[8], wrow[8], q[8];
    load8f(xb + (size_t)s * EMB, xq);
    load8f(Wq, wrow);
    vqc8(xq, wrow, q);

    // ---- stage K/V for all 256 tokens of batch b (waves 0-7; 8-15 idle) ----
    if (tid < 512) {
        const int t = tid & 255;
        float xs[8], kv[8];
        load8f(xb + (size_t)t * EMB, xs);
        if (tid < 256) {
            load8f(Wk, wrow);
            vqc8(xs, wrow, kv);
            store8f(&Ks[t][0], kv);
        } else {
            load8f(Wv, wrow);
            vqc8(xs, wrow, kv);
            store8f(&Vs[t][0], kv);
        }
    }
    __syncthreads();

    // ---- attention partial over my 32-key slice ----
    // exp2 with 1/sqrt(dk)*log2(e) folded into qh (softmax is base-invariant);
    // |sc| <= 2.9 in base-2 so plain exp2-sum is exact-safe.
    const int ho = 4 * h;
    float qh[4];
#pragma unroll
    for (int d = 0; d < 4; ++d) qh[d] = q[ho + d] * (0.5f * 1.44269504f);

    float l = 0.f, acc0 = 0.f, acc1 = 0.f, acc2 = 0.f, acc3 = 0.f;
    const int k0 = j * 32;
#pragma unroll 8
    for (int kk = k0; kk < k0 + 32; ++kk) {
        float4 kr = *reinterpret_cast<const float4*>(&Ks[kk][ho]);  // broadcast
        float4 vr = *reinterpret_cast<const float4*>(&Vs[kk][ho]);
        float sc = qh[0] * kr.x + qh[1] * kr.y + qh[2] * kr.z + qh[3] * kr.w;
        float e  = __builtin_amdgcn_exp2f(sc);   // v_exp_f32
        l    += e;
        acc0 += e * vr.x;
        acc1 += e * vr.y;
        acc2 += e * vr.z;
        acc3 += e * vr.w;
    }
    P[j][p][0] = l;
    P[j][p][1] = acc0;
    P[j][p][2] = acc1;
    P[j][p][3] = acc2;
    P[j][p][4] = acc3;
    __syncthreads();

    // ---- reduce splits: one thread per (token,head) pair -> Cs ----
    if (tid < 128) {
        float ll = 0.f, a0 = 0.f, a1 = 0.f, a2 = 0.f, a3 = 0.f;
#pragma unroll
        for (int jj = 0; jj < NSPLIT; ++jj) {
            ll += P[jj][tid][0];
            a0 += P[jj][tid][1];
            a1 += P[jj][tid][2];
            a2 += P[jj][tid][3];
            a3 += P[jj][tid][4];
        }
        const int sl2 = tid & 63;
        const int ho2 = 4 * (tid >> 6);
        float inv = 1.f / ll;
        Cs[sl2][ho2 + 0] = a0 * inv;
        Cs[sl2][ho2 + 1] = a1 * inv;
        Cs[sl2][ho2 + 2] = a2 * inv;
        Cs[sl2][ho2 + 3] = a3 * inv;
    }
    __syncthreads();

    // ---- MLP tail, one thread per owned token (wave 0) ----
    if (tid < QG) {
        float ctx[8];
        load8f(&Cs[tid][0], ctx);

        float ao[8];
        load8f(Wc, wrow);
        vqc8(ctx, wrow, ao);

        // reload residual input (L1-hot) instead of keeping xq live all kernel
        float xr[8];
        load8f(xb + (size_t)(g * QG + tid) * EMB, xr);

        float r[8];
#pragma unroll
        for (int i = 0; i < 8; ++i) r[i] = xr[i] + ao[i];

        float gg[8], be[8], x1[8];
        load8f(g1, gg); load8f(be1, be);
        ln8(r, gg, be, x1);

        // hv = x1 @ w1.T + b1  (weights loaded 8-at-a-time: keeps VGPR low)
        float bias[8];
        load8f(b1, bias);
        float hv[8];
#pragma unroll
        for (int jj = 0; jj < 8; ++jj) {
            float wr[8];
            load8f(w1 + jj * 8, wr);
            float a = bias[jj];
#pragma unroll
            for (int i = 0; i < 8; ++i) a += x1[i] * wr[i];
            hv[jj] = a;
        }

        float hq[8];
        load8f(Wf, wrow);
        vqc8(hv, wrow, hq);

        // ff = hq @ w2.T + b2 ; residual ; LN2
        load8f(b2, bias);
        float r2[8];
#pragma unroll
        for (int jj = 0; jj < 8; ++jj) {
            float wr[8];
            load8f(w2 + jj * 8, wr);
            float a = bias[jj];
#pragma unroll
            for (int i = 0; i < 8; ++i) a += hq[i] * wr[i];
            r2[jj] = x1[jj] + a;
        }

        float o[8];
        load8f(g2, gg); load8f(be2, be);
        ln8(r2, gg, be, o);

        store8f(out + ((size_t)(b * SEQ + g * QG + tid)) * EMB, o);
    }
}

extern "C" void kernel_launch(void* const* d_in, const int* in_sizes, int n_in,
                              void* d_out, int out_size, void* d_ws, size_t ws_size,
                              hipStream_t stream) {
    const float* x   = (const float*)d_in[0];
    const float* Wq  = (const float*)d_in[1];
    const float* Wk  = (const float*)d_in[2];
    const float* Wv  = (const float*)d_in[3];
    const float* Wc  = (const float*)d_in[4];
    const float* Wf  = (const float*)d_in[5];
    const float* w1  = (const float*)d_in[6];
    const float* b1  = (const float*)d_in[7];
    const float* w2  = (const float*)d_in[8];
    const float* b2  = (const float*)d_in[9];
    const float* g1  = (const float*)d_in[10];
    const float* be1 = (const float*)d_in[11];
    const float* g2  = (const float*)d_in[12];
    const float* be2 = (const float*)d_in[13];
    float* out = (float*)d_out;

    const int B = in_sizes[0] / (SEQ * EMB);   // 64
    vitq_kernel<<<B * 4, 1024, 0, stream>>>(x, Wq, Wk, Wv, Wc, Wf, w1, b1, w2, b2,
                                            g1, be1, g2, be2, out);
}